// Round 8
// baseline (414.789 us; speedup 1.0000x reference)
//
#include <hip/hip_runtime.h>
#include <hip/hip_fp16.h>

#define N_NODES 100000
#define N_EDGES 3200000

#define NBLK_P 320
#define SLICE4 (N_EDGES / 4 / NBLK_P)       // 2500 int4 per partition block (exact)
#define NBKT 512
#define BSHIFT 8                             // 256 nodes per coarse bucket
#define NBKT_USED ((N_NODES + 255) / 256)    // 391
#define EL_CAP 12288                         // LDS edge cache (48 KB); mean bucket = 8192

// ================= CSR build: two-level counting sort (no global atomics) =================
// packed edge int: src | (dst&255)<<17   (src<2^17, dloc<2^8)

__global__ __launch_bounds__(256) void k_coarse_hist(const int4* __restrict__ dst4,
                                                     int* __restrict__ blockHist) {
    __shared__ int h[NBKT];
    int t = threadIdx.x;
    h[t] = 0; h[t + 256] = 0;
    __syncthreads();
    int base = blockIdx.x * SLICE4;
    for (int i = t; i < SLICE4; i += 256) {
        int4 d = dst4[base + i];
        atomicAdd(&h[d.x >> BSHIFT], 1);
        atomicAdd(&h[d.y >> BSHIFT], 1);
        atomicAdd(&h[d.z >> BSHIFT], 1);
        atomicAdd(&h[d.w >> BSHIFT], 1);
    }
    __syncthreads();
    blockHist[blockIdx.x * NBKT + t] = h[t];
    blockHist[blockIdx.x * NBKT + t + 256] = h[t + 256];
}

// column scan: per-(block,bucket) placement offsets + coarseStart; 1024 thr (2 chunks x 512 buckets)
__global__ __launch_bounds__(1024) void k_colscan(int* __restrict__ blockHist,
                                                  int* __restrict__ coarseStart) {
    __shared__ int part[2][NBKT];
    __shared__ int s[NBKT];
    __shared__ int totA[NBKT];
    int tid = threadIdx.x;
    int b = tid & 511, q = tid >> 9;
    const int QR = NBLK_P / 2;  // 160
    int sum = 0;
    for (int r = q * QR; r < (q + 1) * QR; ++r) sum += blockHist[r * NBKT + b];
    part[q][b] = sum;
    __syncthreads();
    if (q == 0) {
        int tot = part[0][b] + part[1][b];
        s[b] = tot;
        totA[b] = tot;
    }
    __syncthreads();
    for (int off = 1; off < NBKT; off <<= 1) {
        int v = 0;
        if (q == 0 && b >= off) v = s[b - off];
        __syncthreads();
        if (q == 0) s[b] += v;
        __syncthreads();
    }
    int excl = s[b] - totA[b];  // exclusive prefix for bucket b (valid for both q)
    if (q == 0) {
        coarseStart[b] = excl;
        if (b == 0) coarseStart[NBKT] = N_EDGES;
    }
    int run = excl;
    if (q == 1) run += part[0][b];
    for (int r = q * QR; r < (q + 1) * QR; ++r) {
        int v = blockHist[r * NBKT + b];
        blockHist[r * NBKT + b] = run;
        run += v;
    }
}

// partition packed edges into coarse-bucket-sorted order via LDS cursors
__global__ __launch_bounds__(256) void k_partition(const int4* __restrict__ src4,
                                                   const int4* __restrict__ dst4,
                                                   const int* __restrict__ blockHist,
                                                   int* __restrict__ sorted) {
    __shared__ int cur[NBKT];
    int t = threadIdx.x;
    cur[t] = blockHist[blockIdx.x * NBKT + t];
    cur[t + 256] = blockHist[blockIdx.x * NBKT + t + 256];
    __syncthreads();
    int base = blockIdx.x * SLICE4;
    for (int i = t; i < SLICE4; i += 256) {
        int4 d = dst4[base + i];
        int4 s = src4[base + i];
        int p;
        p = atomicAdd(&cur[d.x >> BSHIFT], 1); sorted[p] = s.x | ((d.x & 255) << 17);
        p = atomicAdd(&cur[d.y >> BSHIFT], 1); sorted[p] = s.y | ((d.y & 255) << 17);
        p = atomicAdd(&cur[d.z >> BSHIFT], 1); sorted[p] = s.z | ((d.z & 255) << 17);
        p = atomicAdd(&cur[d.w >> BSHIFT], 1); sorted[p] = s.w | ((d.w & 255) << 17);
    }
}

// per-bucket: LDS-staged fine hist + scan -> rowstart/dinv, scatter srcs, fused x->fp16 scale
__global__ __launch_bounds__(256) void k_fine(const int* __restrict__ sorted,
                                              const int* __restrict__ coarseStart,
                                              const float4* __restrict__ x4,
                                              int* __restrict__ rowstart,
                                              float* __restrict__ dinvg,
                                              int* __restrict__ csr_src,
                                              int4* __restrict__ xs) {
    __shared__ int eL[EL_CAP];
    __shared__ int h[256];
    __shared__ int pairsc[256];
    __shared__ int offs[256];
    __shared__ float dloc[256];
    int t = threadIdx.x;
    int bkt = blockIdx.x;
    int beg = coarseStart[bkt], end = coarseStart[bkt + 1];
    int cnt = end - beg;
    bool inLds = (cnt <= EL_CAP);
    h[t] = 0;
    __syncthreads();
    if (inLds) {
        for (int i = t; i < cnt; i += 256) eL[i] = sorted[beg + i];
        __syncthreads();
        for (int i = t; i < cnt; i += 256) atomicAdd(&h[eL[i] >> 17], 1);
    } else {
        for (int i = beg + t; i < end; i += 256) atomicAdd(&h[sorted[i] >> 17], 1);
    }
    __syncthreads();
    int pv = h[t];
    pairsc[t] = pv;
    __syncthreads();
    for (int off = 1; off < 256; off <<= 1) {
        int v = (t >= off) ? pairsc[t - off] : 0;
        __syncthreads();
        pairsc[t] += v;
        __syncthreads();
    }
    int e0 = pairsc[t] - pv;  // exclusive
    offs[t] = e0;
    int n0 = bkt << BSHIFT;
    int nvalid = N_NODES - n0;
    if (nvalid > 256) nvalid = 256;
    if (t < nvalid) {
        rowstart[n0 + t] = beg + e0;
        float dv = rsqrtf((float)(pv + 1));
        dloc[t] = dv;
        dinvg[n0 + t] = dv;
    }
    if (bkt == 0 && t == 0) rowstart[N_NODES] = N_EDGES;
    __syncthreads();
    // scatter srcs into csr_src (writes confined to [beg,end): L2-resident window)
    if (inLds) {
        for (int i = t; i < cnt; i += 256) {
            int pk = eL[i];
            int p = atomicAdd(&offs[pk >> 17], 1);
            csr_src[beg + p] = pk & 0x1FFFF;
        }
    } else {
        for (int i = beg + t; i < end; i += 256) {
            int pk = sorted[i];
            int p = atomicAdd(&offs[pk >> 17], 1);
            csr_src[beg + p] = pk & 0x1FFFF;
        }
    }
    // fused scale: xs[row] = fp16(dinv[row] * x[row]) for this bucket's rows (8 int4 per row)
    for (int i = t; i < nvalid * 16; i += 256) {
        int local = i >> 4;
        int qq = i & 15;
        float d = dloc[local];
        float4 v = x4[(long long)(n0 + local) * 16 + qq];
        __half2 lo = __float22half2_rn(make_float2(v.x * d, v.y * d));
        __half2 hi = __float22half2_rn(make_float2(v.z * d, v.w * d));
        int4 pk;
        pk.x = *(int*)&lo;
        pk.y = *(int*)&hi;
        // store two Half4 (16B granularity handled below): write as 8B pairs
        ((int2*)xs)[(long long)(n0 + local) * 16 + qq] = make_int2(pk.x, pk.y);
    }
}

// ---------------- split-feature gather (fp16 in), half-row = 64B = one cache line ----------------
// 4 lanes x 16B per row-half, 16 edges in flight per wave
// acc = xs_half[node] (self) + sum_src xs_half[src];  out = dinv[node]*acc (+bias)

__device__ __forceinline__ void gather_half_core(
    const int* __restrict__ rowstart, const int* __restrict__ csr_src,
    const int4* __restrict__ xs8, int hoff, int node, int lane, float acc[8])
{
    int q = lane & 3;    // int4 slot within the 64B half-row
    int eg = lane >> 2;  // 0..15: edge slot within each group of 16
    int beg = rowstart[node];
    int deg = rowstart[node + 1] - beg;
#pragma unroll
    for (int k = 0; k < 8; ++k) acc[k] = 0.f;
    if (eg == 0) {
        int4 v = xs8[((long long)node << 3) + hoff + q];
        float2 f0 = __half22float2(*(__half2*)&v.x);
        float2 f1 = __half22float2(*(__half2*)&v.y);
        float2 f2 = __half22float2(*(__half2*)&v.z);
        float2 f3 = __half22float2(*(__half2*)&v.w);
        acc[0] = f0.x; acc[1] = f0.y; acc[2] = f1.x; acc[3] = f1.y;
        acc[4] = f2.x; acc[5] = f2.y; acc[6] = f3.x; acc[7] = f3.y;
    }
    for (int base = 0; base < deg; base += 64) {
        int rem = deg - base;
        if (rem > 64) rem = 64;
        int mye = (lane < rem) ? csr_src[beg + base + lane] : 0;  // coalesced
        int nj = (rem + 15) >> 4;
        for (int j = 0; j < nj; ++j) {
            int eidx = (j << 4) + eg;
            int s = __shfl(mye, eidx);
            if (eidx < rem) {
                int4 v = xs8[((long long)s << 3) + hoff + q];
                float2 f0 = __half22float2(*(__half2*)&v.x);
                float2 f1 = __half22float2(*(__half2*)&v.y);
                float2 f2 = __half22float2(*(__half2*)&v.z);
                float2 f3 = __half22float2(*(__half2*)&v.w);
                acc[0] += f0.x; acc[1] += f0.y; acc[2] += f1.x; acc[3] += f1.y;
                acc[4] += f2.x; acc[5] += f2.y; acc[6] += f3.x; acc[7] += f3.y;
            }
        }
    }
#pragma unroll
    for (int k = 0; k < 8; ++k) {
        acc[k] += __shfl_xor(acc[k], 4);
        acc[k] += __shfl_xor(acc[k], 8);
        acc[k] += __shfl_xor(acc[k], 16);
        acc[k] += __shfl_xor(acc[k], 32);
    }
}

// layer-1 variant: writes fp16 (8 halves = int4), scaled by dinv, no bias
__global__ __launch_bounds__(256) void k_gather_half_h16(
    const int* __restrict__ rowstart, const int* __restrict__ csr_src,
    const float* __restrict__ dinv, const int4* __restrict__ xs8,
    int hoff, int4* __restrict__ aggh)
{
    int node = blockIdx.x * 4 + (threadIdx.x >> 6);
    if (node >= N_NODES) return;
    int lane = threadIdx.x & 63;
    float acc[8];
    gather_half_core(rowstart, csr_src, xs8, hoff, node, lane, acc);
    if ((lane >> 2) == 0) {
        float d = dinv[node];
        __half2 h0 = __float22half2_rn(make_float2(d * acc[0], d * acc[1]));
        __half2 h1 = __float22half2_rn(make_float2(d * acc[2], d * acc[3]));
        __half2 h2 = __float22half2_rn(make_float2(d * acc[4], d * acc[5]));
        __half2 h3 = __float22half2_rn(make_float2(d * acc[6], d * acc[7]));
        int4 o;
        o.x = *(int*)&h0; o.y = *(int*)&h1; o.z = *(int*)&h2; o.w = *(int*)&h3;
        aggh[((long long)node << 3) + hoff + (lane & 3)] = o;
    }
}

// layer-2 variant: writes f32 out with dinv scale + bias
__global__ __launch_bounds__(256) void k_gather_half_f32(
    const int* __restrict__ rowstart, const int* __restrict__ csr_src,
    const float* __restrict__ dinv, const int4* __restrict__ xs8,
    int hoff, const float4* __restrict__ bias_h, float4* __restrict__ out4)
{
    int node = blockIdx.x * 4 + (threadIdx.x >> 6);
    if (node >= N_NODES) return;
    int lane = threadIdx.x & 63;
    float acc[8];
    gather_half_core(rowstart, csr_src, xs8, hoff, node, lane, acc);
    int q = lane & 3;
    if ((lane >> 2) == 0) {
        float d = dinv[node];
        float4 b0 = bias_h[q * 2];
        float4 b1 = bias_h[q * 2 + 1];
        out4[(long long)node * 16 + hoff * 2 + q * 2] =
            make_float4(d * acc[0] + b0.x, d * acc[1] + b0.y, d * acc[2] + b0.z, d * acc[3] + b0.w);
        out4[(long long)node * 16 + hoff * 2 + q * 2 + 1] =
            make_float4(d * acc[4] + b1.x, d * acc[5] + b1.y, d * acc[6] + b1.z, d * acc[7] + b1.w);
    }
}

// ---------------- fused GEMM: P = fp16(dinv * (relu(A@W1 + b1) @ W2)), A fp16 ----------------

#define GTILE 128
__global__ __launch_bounds__(256) void k_fused_gemm(
    const int4* __restrict__ Ah, const float* __restrict__ W1,
    const float* __restrict__ b1, const float* __restrict__ W2,
    const float* __restrict__ dinv, int2* __restrict__ P)
{
    __shared__ float sBuf[128][GTILE];  // rows 0..63: A^T[k][r]; later 0..127: H^T[c][r]
    int tid = threadIdx.x;
    int R0 = blockIdx.x * GTILE;

    // stage A^T: thread t -> row t>>1, k-range (t&1)*32 .. +31  (32 halves = 4 int4)
    {
        int row = tid >> 1;
        int kb = (tid & 1) * 32;
        int grow = R0 + row;
        if (grow < N_NODES) {
#pragma unroll
            for (int qq = 0; qq < 4; ++qq) {
                int4 v = Ah[((long long)grow << 3) + (tid & 1) * 4 + qq];
                float2 f0 = __half22float2(*(__half2*)&v.x);
                float2 f1 = __half22float2(*(__half2*)&v.y);
                float2 f2 = __half22float2(*(__half2*)&v.z);
                float2 f3 = __half22float2(*(__half2*)&v.w);
                int k = kb + qq * 8;
                sBuf[k + 0][row] = f0.x; sBuf[k + 1][row] = f0.y;
                sBuf[k + 2][row] = f1.x; sBuf[k + 3][row] = f1.y;
                sBuf[k + 4][row] = f2.x; sBuf[k + 5][row] = f2.y;
                sBuf[k + 6][row] = f3.x; sBuf[k + 7][row] = f3.y;
            }
        } else {
#pragma unroll
            for (int qq = 0; qq < 32; ++qq) sBuf[kb + qq][row] = 0.f;
        }
    }
    __syncthreads();

    int rg = tid & 15;
    int cg = tid >> 4;
    int r0 = rg * 8;

    float acc[8][8];
#pragma unroll
    for (int i = 0; i < 8; ++i)
#pragma unroll
        for (int j = 0; j < 8; ++j) acc[i][j] = 0.f;
    {
        int c0 = cg * 8;
#pragma unroll 4
        for (int k = 0; k < 64; ++k) {
            float4 a0 = *(const float4*)&sBuf[k][r0];
            float4 a1 = *(const float4*)&sBuf[k][r0 + 4];
            float4 w0 = *(const float4*)&W1[k * 128 + c0];
            float4 w1 = *(const float4*)&W1[k * 128 + c0 + 4];
            float av[8] = {a0.x, a0.y, a0.z, a0.w, a1.x, a1.y, a1.z, a1.w};
            float wv[8] = {w0.x, w0.y, w0.z, w0.w, w1.x, w1.y, w1.z, w1.w};
#pragma unroll
            for (int i = 0; i < 8; ++i)
#pragma unroll
                for (int j = 0; j < 8; ++j) acc[i][j] += av[i] * wv[j];
        }
    }
    __syncthreads();

    {
        int c0 = cg * 8;
#pragma unroll
        for (int j = 0; j < 8; ++j) {
            float bb = b1[c0 + j];
            float4 h0, h1;
            h0.x = fmaxf(acc[0][j] + bb, 0.f);
            h0.y = fmaxf(acc[1][j] + bb, 0.f);
            h0.z = fmaxf(acc[2][j] + bb, 0.f);
            h0.w = fmaxf(acc[3][j] + bb, 0.f);
            h1.x = fmaxf(acc[4][j] + bb, 0.f);
            h1.y = fmaxf(acc[5][j] + bb, 0.f);
            h1.z = fmaxf(acc[6][j] + bb, 0.f);
            h1.w = fmaxf(acc[7][j] + bb, 0.f);
            *(float4*)&sBuf[c0 + j][r0] = h0;
            *(float4*)&sBuf[c0 + j][r0 + 4] = h1;
        }
    }
    __syncthreads();

    {
        int c0 = cg * 4;
        float acc2[8][4];
#pragma unroll
        for (int i = 0; i < 8; ++i)
#pragma unroll
            for (int j = 0; j < 4; ++j) acc2[i][j] = 0.f;
#pragma unroll 4
        for (int k = 0; k < 128; ++k) {
            float4 a0 = *(const float4*)&sBuf[k][r0];
            float4 a1 = *(const float4*)&sBuf[k][r0 + 4];
            float4 w = *(const float4*)&W2[k * 64 + c0];
            float av[8] = {a0.x, a0.y, a0.z, a0.w, a1.x, a1.y, a1.z, a1.w};
            float wv[4] = {w.x, w.y, w.z, w.w};
#pragma unroll
            for (int i = 0; i < 8; ++i)
#pragma unroll
                for (int j = 0; j < 4; ++j) acc2[i][j] += av[i] * wv[j];
        }
#pragma unroll
        for (int i = 0; i < 8; ++i) {
            int row = R0 + r0 + i;
            if (row < N_NODES) {
                float d = dinv[row];
                __half2 lo = __float22half2_rn(make_float2(d * acc2[i][0], d * acc2[i][1]));
                __half2 hi = __float22half2_rn(make_float2(d * acc2[i][2], d * acc2[i][3]));
                P[(long long)row * 16 + cg] = make_int2(*(int*)&lo, *(int*)&hi);
            }
        }
    }
}

// ---------------- launch ----------------

extern "C" void kernel_launch(void* const* d_in, const int* in_sizes, int n_in,
                              void* d_out, int out_size, void* d_ws, size_t ws_size,
                              hipStream_t stream) {
    const float* x  = (const float*)d_in[0];
    const int*   ei = (const int*)d_in[1];
    const float* W1 = (const float*)d_in[2];
    const float* b1 = (const float*)d_in[3];
    const float* W2 = (const float*)d_in[4];
    const float* b2 = (const float*)d_in[5];
    float* out = (float*)d_out;

    const int* srcE = ei;            // edge_index[0]
    const int* dstE = ei + N_EDGES;  // edge_index[1]

    // workspace layout
    char* w = (char*)d_ws;
    int*   blockHist   = (int*)w;   w += sizeof(int) * NBLK_P * NBKT;
    int*   coarseStart = (int*)w;   w += sizeof(int) * (NBKT + 1);
    int*   rowstart    = (int*)w;   w += sizeof(int) * (N_NODES + 8);
    float* dinv        = (float*)w; w += sizeof(float) * (N_NODES + 8);
    int*   csr_src     = (int*)w;   w += sizeof(int) * N_EDGES;
    int4*  xs          = (int4*)w;  w += 16 * (size_t)N_NODES * 8;   // [N][64] fp16
    // union: sorted (E ints = 12.8MB) dies before aggh (N*64 fp16 = 12.8MB) is written
    int*   sorted      = (int*)w;
    int4*  aggh        = (int4*)w;  w += 16 * (size_t)N_NODES * 8;
    int4*  p2 = xs;  // xs dead after layer-1 gather; reuse for fp16 p2

    // CSR build (no global atomics) + fused dinv/scale
    k_coarse_hist<<<NBLK_P, 256, 0, stream>>>((const int4*)dstE, blockHist);
    k_colscan<<<1, 1024, 0, stream>>>(blockHist, coarseStart);
    k_partition<<<NBLK_P, 256, 0, stream>>>((const int4*)srcE, (const int4*)dstE,
                                            blockHist, sorted);
    k_fine<<<NBKT_USED, 256, 0, stream>>>(sorted, coarseStart, (const float4*)x,
                                          rowstart, dinv, csr_src, xs);

    // layer 1: two half-feature gather passes (fp16 out), then fused GEMMs
    k_gather_half_h16<<<(N_NODES + 3) / 4, 256, 0, stream>>>(rowstart, csr_src, dinv,
                                                             xs, 0, aggh);
    k_gather_half_h16<<<(N_NODES + 3) / 4, 256, 0, stream>>>(rowstart, csr_src, dinv,
                                                             xs, 4, aggh);
    k_fused_gemm<<<(N_NODES + GTILE - 1) / GTILE, 256, 0, stream>>>(aggh, W1, b1, W2,
                                                                    dinv, (int2*)p2);

    // layer 2: two half-feature gather passes into out (+b2)
    k_gather_half_f32<<<(N_NODES + 3) / 4, 256, 0, stream>>>(rowstart, csr_src, dinv,
                                                             p2, 0, (const float4*)b2,
                                                             (float4*)out);
    k_gather_half_f32<<<(N_NODES + 3) / 4, 256, 0, stream>>>(rowstart, csr_src, dinv,
                                                             p2, 4, (const float4*)b2 + 8,
                                                             (float4*)out);
}

// Round 9
// 283.292 us; speedup vs baseline: 1.4642x; 1.4642x over previous
//
#include <hip/hip_runtime.h>
#include <hip/hip_fp16.h>

#define N_NODES 100000
#define N_EDGES 3200000
#define NPAD 100096   // row-padded node count (multiple of 128)

#define NBLK_P 320
#define SLICE4 (N_EDGES / 4 / NBLK_P)       // 2500 int4 per partition block (exact)
#define NBKT 512
#define BSHIFT 8                             // 256 nodes per coarse bucket
#define NBKT_USED ((N_NODES + 255) / 256)    // 391
#define EL_CAP 12288                         // LDS edge cache (48 KB); mean bucket = 8192

using f16x8 = __attribute__((ext_vector_type(8))) _Float16;
using f32x4 = __attribute__((ext_vector_type(4))) float;

// ================= CSR build: two-level counting sort (no global atomics) =================
// packed edge int: src | (dst&255)<<17   (src<2^17, dloc<2^8)

__global__ __launch_bounds__(256) void k_coarse_hist(const int4* __restrict__ dst4,
                                                     int* __restrict__ blockHist) {
    __shared__ int h[NBKT];
    int t = threadIdx.x;
    h[t] = 0; h[t + 256] = 0;
    __syncthreads();
    int base = blockIdx.x * SLICE4;
    for (int i = t; i < SLICE4; i += 256) {
        int4 d = dst4[base + i];
        atomicAdd(&h[d.x >> BSHIFT], 1);
        atomicAdd(&h[d.y >> BSHIFT], 1);
        atomicAdd(&h[d.z >> BSHIFT], 1);
        atomicAdd(&h[d.w >> BSHIFT], 1);
    }
    __syncthreads();
    blockHist[blockIdx.x * NBKT + t] = h[t];
    blockHist[blockIdx.x * NBKT + t + 256] = h[t + 256];
}

__global__ __launch_bounds__(1024) void k_colscan(int* __restrict__ blockHist,
                                                  int* __restrict__ coarseStart) {
    __shared__ int part[2][NBKT];
    __shared__ int s[NBKT];
    __shared__ int totA[NBKT];
    int tid = threadIdx.x;
    int b = tid & 511, q = tid >> 9;
    const int QR = NBLK_P / 2;  // 160
    int sum = 0;
    for (int r = q * QR; r < (q + 1) * QR; ++r) sum += blockHist[r * NBKT + b];
    part[q][b] = sum;
    __syncthreads();
    if (q == 0) {
        int tot = part[0][b] + part[1][b];
        s[b] = tot;
        totA[b] = tot;
    }
    __syncthreads();
    for (int off = 1; off < NBKT; off <<= 1) {
        int v = 0;
        if (q == 0 && b >= off) v = s[b - off];
        __syncthreads();
        if (q == 0) s[b] += v;
        __syncthreads();
    }
    int excl = s[b] - totA[b];
    if (q == 0) {
        coarseStart[b] = excl;
        if (b == 0) coarseStart[NBKT] = N_EDGES;
    }
    int run = excl;
    if (q == 1) run += part[0][b];
    for (int r = q * QR; r < (q + 1) * QR; ++r) {
        int v = blockHist[r * NBKT + b];
        blockHist[r * NBKT + b] = run;
        run += v;
    }
}

__global__ __launch_bounds__(256) void k_partition(const int4* __restrict__ src4,
                                                   const int4* __restrict__ dst4,
                                                   const int* __restrict__ blockHist,
                                                   int* __restrict__ sorted) {
    __shared__ int cur[NBKT];
    int t = threadIdx.x;
    cur[t] = blockHist[blockIdx.x * NBKT + t];
    cur[t + 256] = blockHist[blockIdx.x * NBKT + t + 256];
    __syncthreads();
    int base = blockIdx.x * SLICE4;
    for (int i = t; i < SLICE4; i += 256) {
        int4 d = dst4[base + i];
        int4 s = src4[base + i];
        int p;
        p = atomicAdd(&cur[d.x >> BSHIFT], 1); sorted[p] = s.x | ((d.x & 255) << 17);
        p = atomicAdd(&cur[d.y >> BSHIFT], 1); sorted[p] = s.y | ((d.y & 255) << 17);
        p = atomicAdd(&cur[d.z >> BSHIFT], 1); sorted[p] = s.z | ((d.z & 255) << 17);
        p = atomicAdd(&cur[d.w >> BSHIFT], 1); sorted[p] = s.w | ((d.w & 255) << 17);
    }
}

// per-bucket: fine hist + scan -> rowstart/dinv, scatter srcs, fused x->fp16 scale
__global__ __launch_bounds__(256) void k_fine(const int* __restrict__ sorted,
                                              const int* __restrict__ coarseStart,
                                              const float4* __restrict__ x4,
                                              int* __restrict__ rowstart,
                                              float* __restrict__ dinvg,
                                              int* __restrict__ csr_src,
                                              int2* __restrict__ xs2) {
    __shared__ int eL[EL_CAP];
    __shared__ int h[256];
    __shared__ int pairsc[256];
    __shared__ int offs[256];
    __shared__ float dloc[256];
    int t = threadIdx.x;
    int bkt = blockIdx.x;
    int beg = coarseStart[bkt], end = coarseStart[bkt + 1];
    int cnt = end - beg;
    bool inLds = (cnt <= EL_CAP);
    h[t] = 0;
    __syncthreads();
    if (inLds) {
        for (int i = t; i < cnt; i += 256) eL[i] = sorted[beg + i];
        __syncthreads();
        for (int i = t; i < cnt; i += 256) atomicAdd(&h[eL[i] >> 17], 1);
    } else {
        for (int i = beg + t; i < end; i += 256) atomicAdd(&h[sorted[i] >> 17], 1);
    }
    __syncthreads();
    int pv = h[t];
    pairsc[t] = pv;
    __syncthreads();
    for (int off = 1; off < 256; off <<= 1) {
        int v = (t >= off) ? pairsc[t - off] : 0;
        __syncthreads();
        pairsc[t] += v;
        __syncthreads();
    }
    int e0 = pairsc[t] - pv;  // exclusive
    offs[t] = e0;
    int n0 = bkt << BSHIFT;
    int nvalid = N_NODES - n0;
    if (nvalid > 256) nvalid = 256;
    if (t < nvalid) {
        rowstart[n0 + t] = beg + e0;
        float dv = rsqrtf((float)(pv + 1));
        dloc[t] = dv;
        dinvg[n0 + t] = dv;
    }
    if (bkt == 0 && t == 0) rowstart[N_NODES] = N_EDGES;
    __syncthreads();
    if (inLds) {
        for (int i = t; i < cnt; i += 256) {
            int pk = eL[i];
            int p = atomicAdd(&offs[pk >> 17], 1);
            csr_src[beg + p] = pk & 0x1FFFF;
        }
    } else {
        for (int i = beg + t; i < end; i += 256) {
            int pk = sorted[i];
            int p = atomicAdd(&offs[pk >> 17], 1);
            csr_src[beg + p] = pk & 0x1FFFF;
        }
    }
    // fused scale: xs[row] = fp16(dinv[row] * x[row]) for this bucket's rows
    for (int i = t; i < nvalid * 16; i += 256) {
        int local = i >> 4;
        int qq = i & 15;
        float d = dloc[local];
        float4 v = x4[(long long)(n0 + local) * 16 + qq];
        __half2 lo = __float22half2_rn(make_float2(v.x * d, v.y * d));
        __half2 hi = __float22half2_rn(make_float2(v.z * d, v.w * d));
        xs2[(long long)(n0 + local) * 16 + qq] = make_int2(*(int*)&lo, *(int*)&hi);
    }
}

// ---------------- full-row gather (fp16 rows = 128B = one line) ----------------
// 8 lanes x 16B per row, 8 edge-rows in flight per wave

__device__ __forceinline__ void gather_core(
    const int* __restrict__ rowstart, const int* __restrict__ csr_src,
    const int4* __restrict__ xs16, int node, int lane, float acc[8])
{
    int qlane = lane & 7;
    int egrp = lane >> 3;
    int beg = rowstart[node];
    int deg = rowstart[node + 1] - beg;
#pragma unroll
    for (int k = 0; k < 8; ++k) acc[k] = 0.f;
    if (egrp == 0) {  // self loop (pre-scaled)
        int4 v = xs16[((long long)node << 3) + qlane];
        float2 f0 = __half22float2(*(__half2*)&v.x);
        float2 f1 = __half22float2(*(__half2*)&v.y);
        float2 f2 = __half22float2(*(__half2*)&v.z);
        float2 f3 = __half22float2(*(__half2*)&v.w);
        acc[0] = f0.x; acc[1] = f0.y; acc[2] = f1.x; acc[3] = f1.y;
        acc[4] = f2.x; acc[5] = f2.y; acc[6] = f3.x; acc[7] = f3.y;
    }
    for (int base = 0; base < deg; base += 64) {
        int rem = deg - base;
        if (rem > 64) rem = 64;
        int mye = (lane < rem) ? csr_src[beg + base + lane] : 0;  // coalesced
        int nj = (rem + 7) >> 3;
        for (int j = 0; j < nj; ++j) {
            int eidx = (j << 3) + egrp;
            int s = __shfl(mye, eidx);
            if (eidx < rem) {
                int4 v = xs16[((long long)s << 3) + qlane];
                float2 f0 = __half22float2(*(__half2*)&v.x);
                float2 f1 = __half22float2(*(__half2*)&v.y);
                float2 f2 = __half22float2(*(__half2*)&v.z);
                float2 f3 = __half22float2(*(__half2*)&v.w);
                acc[0] += f0.x; acc[1] += f0.y; acc[2] += f1.x; acc[3] += f1.y;
                acc[4] += f2.x; acc[5] += f2.y; acc[6] += f3.x; acc[7] += f3.y;
            }
        }
    }
#pragma unroll
    for (int k = 0; k < 8; ++k) {
        acc[k] += __shfl_xor(acc[k], 8);
        acc[k] += __shfl_xor(acc[k], 16);
        acc[k] += __shfl_xor(acc[k], 32);
    }
}

// layer-1: out fp16, dinv-scaled, no bias
__global__ __launch_bounds__(256) void k_gather_h16(
    const int* __restrict__ rowstart, const int* __restrict__ csr_src,
    const float* __restrict__ dinv, const int4* __restrict__ xs16,
    int4* __restrict__ aggh)
{
    int node = blockIdx.x * 4 + (threadIdx.x >> 6);
    if (node >= N_NODES) return;
    int lane = threadIdx.x & 63;
    float acc[8];
    gather_core(rowstart, csr_src, xs16, node, lane, acc);
    if ((lane >> 3) == 0) {
        float d = dinv[node];
        __half2 h0 = __float22half2_rn(make_float2(d * acc[0], d * acc[1]));
        __half2 h1 = __float22half2_rn(make_float2(d * acc[2], d * acc[3]));
        __half2 h2 = __float22half2_rn(make_float2(d * acc[4], d * acc[5]));
        __half2 h3 = __float22half2_rn(make_float2(d * acc[6], d * acc[7]));
        int4 o;
        o.x = *(int*)&h0; o.y = *(int*)&h1; o.z = *(int*)&h2; o.w = *(int*)&h3;
        aggh[((long long)node << 3) + (lane & 7)] = o;
    }
}

// layer-2: out f32 with dinv scale + bias
__global__ __launch_bounds__(256) void k_gather_f32(
    const int* __restrict__ rowstart, const int* __restrict__ csr_src,
    const float* __restrict__ dinv, const int4* __restrict__ xs16,
    const float4* __restrict__ bias4, float4* __restrict__ out4)
{
    int node = blockIdx.x * 4 + (threadIdx.x >> 6);
    if (node >= N_NODES) return;
    int lane = threadIdx.x & 63;
    float acc[8];
    gather_core(rowstart, csr_src, xs16, node, lane, acc);
    int qlane = lane & 7;
    if ((lane >> 3) == 0) {
        float d = dinv[node];
        float4 b0 = bias4[qlane * 2];
        float4 b1 = bias4[qlane * 2 + 1];
        out4[(long long)node * 16 + qlane * 2] =
            make_float4(d * acc[0] + b0.x, d * acc[1] + b0.y, d * acc[2] + b0.z, d * acc[3] + b0.w);
        out4[(long long)node * 16 + qlane * 2 + 1] =
            make_float4(d * acc[4] + b1.x, d * acc[5] + b1.y, d * acc[6] + b1.z, d * acc[7] + b1.w);
    }
}

// ---------------- MFMA fused GEMM: P = fp16(dinv * (relu(A@W1 + b1) @ W2)) ----------------
// A (aggh) fp16 [N][64]; 256 thr = 4 waves; 2 groups of 16 rows per wave -> 128 rows/block.
// Layouts (m89-verified): A-frag lane l: row=l&15, k=(l>>4)*8+i ; B-frag: col=l&15, same k;
// D-frag: row=(l>>4)*4+r, col=l&15.

#define GEMM_GROUPS 2
__global__ __launch_bounds__(256) void k_mfma_gemm(
    const f16x8* __restrict__ aggh8, const float* __restrict__ W1,
    const float* __restrict__ b1g, const float* __restrict__ W2,
    const float* __restrict__ dinv, _Float16* __restrict__ P)
{
    __shared__ _Float16 sW1T[128][72];   // [col][k], padded: 2-way banks max
    __shared__ _Float16 sW2T[64][136];   // [col][k]
    __shared__ _Float16 sH[4][16][136];  // per-wave H tile [row][col]
    int tid = threadIdx.x;
    for (int i = tid; i < 64 * 128; i += 256) {
        int k = i >> 7, c = i & 127;
        sW1T[c][k] = (_Float16)W1[i];
    }
    for (int i = tid; i < 128 * 64; i += 256) {
        int k = i >> 6, c = i & 63;
        sW2T[c][k] = (_Float16)W2[i];
    }
    __syncthreads();
    int w = tid >> 6;
    int l = tid & 63;
    int lr = l & 15;   // A-row / B-col within 16
    int lk = l >> 4;   // k-group 0..3

    for (int g = 0; g < GEMM_GROUPS; ++g) {
        int base = blockIdx.x * (64 * GEMM_GROUPS) + (w * GEMM_GROUPS + g) * 16;
        int row = base + lr;
        f16x8 a0 = aggh8[(long long)row * 8 + lk];        // k 0..31
        f16x8 a1 = aggh8[(long long)row * 8 + 4 + lk];    // k 32..63
        // phase 1: H = relu(A@W1 + b1) -> sH (wave-private)
        for (int nt = 0; nt < 8; ++nt) {
            f32x4 acc = {0.f, 0.f, 0.f, 0.f};
            f16x8 bf0 = *(const f16x8*)&sW1T[nt * 16 + lr][lk * 8];
            f16x8 bf1 = *(const f16x8*)&sW1T[nt * 16 + lr][32 + lk * 8];
            acc = __builtin_amdgcn_mfma_f32_16x16x32_f16(a0, bf0, acc, 0, 0, 0);
            acc = __builtin_amdgcn_mfma_f32_16x16x32_f16(a1, bf1, acc, 0, 0, 0);
            float bb = b1g[nt * 16 + lr];
#pragma unroll
            for (int r = 0; r < 4; ++r)
                sH[w][4 * lk + r][nt * 16 + lr] = (_Float16)fmaxf(acc[r] + bb, 0.f);
        }
        // phase 2: P = dinv * (H@W2)  (sH wave-private: lgkmcnt ordering suffices)
        f16x8 ha[4];
#pragma unroll
        for (int ks = 0; ks < 4; ++ks)
            ha[ks] = *(const f16x8*)&sH[w][lr][ks * 32 + lk * 8];
        float dv[4];
#pragma unroll
        for (int r = 0; r < 4; ++r) dv[r] = dinv[base + 4 * lk + r];
        for (int nt = 0; nt < 4; ++nt) {
            f32x4 acc = {0.f, 0.f, 0.f, 0.f};
#pragma unroll
            for (int ks = 0; ks < 4; ++ks) {
                f16x8 bf = *(const f16x8*)&sW2T[nt * 16 + lr][ks * 32 + lk * 8];
                acc = __builtin_amdgcn_mfma_f32_16x16x32_f16(ha[ks], bf, acc, 0, 0, 0);
            }
#pragma unroll
            for (int r = 0; r < 4; ++r) {
                int rr = base + 4 * lk + r;
                if (rr < N_NODES)
                    P[(long long)rr * 64 + nt * 16 + lr] = (_Float16)(dv[r] * acc[r]);
            }
        }
    }
}

// ---------------- launch ----------------

extern "C" void kernel_launch(void* const* d_in, const int* in_sizes, int n_in,
                              void* d_out, int out_size, void* d_ws, size_t ws_size,
                              hipStream_t stream) {
    const float* x  = (const float*)d_in[0];
    const int*   ei = (const int*)d_in[1];
    const float* W1 = (const float*)d_in[2];
    const float* b1 = (const float*)d_in[3];
    const float* W2 = (const float*)d_in[4];
    const float* b2 = (const float*)d_in[5];
    float* out = (float*)d_out;

    const int* srcE = ei;            // edge_index[0]
    const int* dstE = ei + N_EDGES;  // edge_index[1]

    // workspace layout
    char* w = (char*)d_ws;
    int*   blockHist   = (int*)w;   w += sizeof(int) * NBLK_P * NBKT;
    int*   coarseStart = (int*)w;   w += sizeof(int) * (NBKT + 1);
    int*   rowstart    = (int*)w;   w += sizeof(int) * (N_NODES + 8);
    float* dinv        = (float*)w; w += sizeof(float) * (NPAD + 128);
    int*   csr_src     = (int*)w;   w += sizeof(int) * N_EDGES;
    char*  xsbuf       = w;         w += 128 * (size_t)NPAD;   // [N][64] fp16
    // union: sorted (E ints = 12.8MB) dies before aggh (NPAD*128B) is written
    char*  ubuf        = w;         w += 128 * (size_t)NPAD;
    int*   sorted = (int*)ubuf;
    int4*  aggh   = (int4*)ubuf;
    int4*  xs     = (int4*)xsbuf;
    _Float16* p2  = (_Float16*)xsbuf;  // xs dead after layer-1 gather; reuse for fp16 p2

    // CSR build (no global atomics) + fused dinv/scale
    k_coarse_hist<<<NBLK_P, 256, 0, stream>>>((const int4*)dstE, blockHist);
    k_colscan<<<1, 1024, 0, stream>>>(blockHist, coarseStart);
    k_partition<<<NBLK_P, 256, 0, stream>>>((const int4*)srcE, (const int4*)dstE,
                                            blockHist, sorted);
    k_fine<<<NBKT_USED, 256, 0, stream>>>(sorted, coarseStart, (const float4*)x,
                                          rowstart, dinv, csr_src, (int2*)xsbuf);

    // layer 1: full-row gather (fp16 out), then MFMA fused GEMMs -> p2 (fp16, dinv-scaled)
    k_gather_h16<<<(N_NODES + 3) / 4, 256, 0, stream>>>(rowstart, csr_src, dinv, xs, aggh);
    k_mfma_gemm<<<(NPAD / (64 * GEMM_GROUPS)), 256, 0, stream>>>((const f16x8*)aggh, W1, b1,
                                                                 W2, dinv, p2);

    // layer 2: full-row gather into out (+b2)
    k_gather_f32<<<(N_NODES + 3) / 4, 256, 0, stream>>>(rowstart, csr_src, dinv,
                                                        (const int4*)p2,
                                                        (const float4*)b2, (float4*)out);
}